// Round 5
// baseline (483.600 us; speedup 1.0000x reference)
//
#include <hip/hip_runtime.h>

#define NN 100000
#define NE 3200000
#define NG 512
#define NCB 782           // coarse buckets of 128 nodes: ceil(100000/128)
#define BN_EPS 1e-5f
#define NSLICE 4          // feature slices: 16 feats = 32B per row-slice
#define SLICE_U32 8       // u32 words per row-slice
#define AGG_GRID 12504    // 1563*8: slice = (b&7)>>1 (XCD-bound), 3126 node-groups/slice

typedef unsigned short u16;
typedef unsigned int u32;

__device__ __forceinline__ u16 f2bf(float f) {
    u32 u = __float_as_uint(f);
    u += 0x7FFF + ((u >> 16) & 1);  // RNE
    return (u16)(u >> 16);
}

// ================= coarse histogram (LDS-privatized) =================
__global__ __launch_bounds__(256) void k_chist(const int* __restrict__ dst, int* __restrict__ ccount) {
    __shared__ int h[NCB];
    int t = threadIdx.x;
    for (int i = t; i < NCB; i += 256) h[i] = 0;
    __syncthreads();
    int stride = gridDim.x * 256;
    for (int e = blockIdx.x * 256 + t; e < NE; e += stride)
        atomicAdd(&h[dst[e] >> 7], 1);
    __syncthreads();
    for (int i = t; i < NCB; i += 256)
        if (h[i]) atomicAdd(&ccount[i], h[i]);
}

// ========== scan coarse counts -> cbase, padded fine bases, global cursors ==========
// also zeroes the 4 per-slice sentinel rows of hp (row NN of each slice)
__global__ __launch_bounds__(256) void k_cscan(const int* __restrict__ ccount, int* __restrict__ cbase,
                                               int* __restrict__ fbase, int* __restrict__ gcur,
                                               u32* __restrict__ hpz) {
    __shared__ int sh[256], sh2[256];
    int t = threadIdx.x;
    if (t < NSLICE * SLICE_U32) {
        int slice = t >> 3, w = t & 7;
        hpz[(size_t)slice * (NN + 1) * SLICE_U32 + (size_t)NN * SLICE_U32 + w] = 0;
    }
    int v[4], w[4];
    int s = 0, s2 = 0;
#pragma unroll
    for (int j = 0; j < 4; j++) {
        int idx = t * 4 + j;
        int c = (idx < NCB) ? ccount[idx] : 0;
        v[j] = c;
        w[j] = (idx < NCB) ? ((c + 387) & ~3) : 0;  // <=3 pad per node * 128 nodes, x4 aligned
        s += v[j]; s2 += w[j];
    }
    sh[t] = s; sh2[t] = s2;
    __syncthreads();
    for (int off = 1; off < 256; off <<= 1) {
        int x = (t >= off) ? sh[t - off] : 0;
        int x2 = (t >= off) ? sh2[t - off] : 0;
        __syncthreads();
        sh[t] += x; sh2[t] += x2;
        __syncthreads();
    }
    int run = sh[t] - s, run2 = sh2[t] - s2;
#pragma unroll
    for (int j = 0; j < 4; j++) {
        int idx = t * 4 + j;
        if (idx < NCB) { cbase[idx] = run; gcur[idx] = run; fbase[idx] = run2; }
        run += v[j]; run2 += w[j];
    }
    if (t == 255) cbase[NCB] = run;  // == NE
}

// ========== pass 1: coarse binning ==========
#define P1_CHUNK 16384
__global__ __launch_bounds__(1024) void k_p1(const int* __restrict__ src, const int* __restrict__ dst,
                                             int* __restrict__ gcur, int* __restrict__ esc) {
    __shared__ int ccur[NCB];
    const int t = threadIdx.x;
    const int e0 = blockIdx.x * P1_CHUNK;
    for (int i = t; i < NCB; i += 1024) ccur[i] = 0;
    __syncthreads();
    int n = NE - e0; if (n > P1_CHUNK) n = P1_CHUNK;
    // phase 1: block-local histogram
    for (int idx = t; idx < n; idx += 1024)
        atomicAdd(&ccur[dst[e0 + idx] >> 7], 1);
    __syncthreads();
    // phase 2: one global reservation per (block,bucket)
    for (int i = t; i < NCB; i += 1024) {
        int c = ccur[i];
        ccur[i] = (c > 0) ? atomicAdd(&gcur[i], c) : 0;
    }
    __syncthreads();
    // phase 3: scatter (re-read src/dst — L3-hot)
    for (int idx = t; idx < n; idx += 1024) {
        int dd = dst[e0 + idx];
        int s = src[e0 + idx];
        int pos = atomicAdd(&ccur[dd >> 7], 1);
        esc[pos] = s | ((dd & 127) << 17);  // 17b src | 7b dstLocal
    }
}

// ========== pass 2: fine per-node CSR within each coarse bucket; emits offs/cntp/dinv ==========
__global__ __launch_bounds__(256) void k_p2(const int* __restrict__ esc, const int* __restrict__ cbase,
                                            const int* __restrict__ fbase, int* __restrict__ esf,
                                            int* __restrict__ offs, int* __restrict__ cntp,
                                            float* __restrict__ dinv) {
    __shared__ int lcnt[128], loff[128], lcur[128];
    int t = threadIdx.x, b = blockIdx.x;
    int c0 = cbase[b], c1 = cbase[b + 1];
    if (t < 128) lcnt[t] = 0;
    __syncthreads();
    for (int i = c0 + t; i < c1; i += 256) atomicAdd(&lcnt[esc[i] >> 17], 1);
    __syncthreads();
    int p = 0, cnt = 0;
    if (t < 128) { cnt = lcnt[t]; p = (cnt + 3) & ~3; loff[t] = p; }
    __syncthreads();
    for (int off = 1; off < 128; off <<= 1) {
        int x = (t >= off && t < 128) ? loff[t - off] : 0;
        __syncthreads();
        if (t < 128) loff[t] += x;
        __syncthreads();
    }
    int fb = fbase[b];
    int node = (b << 7) + t;
    if (t < 128) {
        int o = fb + loff[t] - p;
        lcur[t] = o;
        if (node < NN) {
            offs[node] = o;
            cntp[node] = p;
            dinv[node] = rsqrtf((float)(cnt + 1));  // +1 self-loop
            for (int q = cnt; q < p; q++) esf[o + q] = NN;  // sentinel -> zero row
        }
    }
    __syncthreads();
    for (int i = c0 + t; i < c1; i += 256) {
        int rec = esc[i];
        int pos = atomicAdd(&lcur[rec >> 17], 1);
        esf[pos] = rec & 0x1FFFF;
    }
}

// ===== GEMM: hp_s[slice][M][16] = bf16( (X[M][K] @ W[K][64]) * dinv[row] ), feature-sliced =====
template <int K>
__global__ __launch_bounds__(256) void k_gemm(const float* __restrict__ X,
                                              const float* __restrict__ W,
                                              const float* __restrict__ dinv,
                                              u16* __restrict__ hp, int M) {
    __shared__ float xs[128 * 68];
    __shared__ float ws[64 * 64];
    const int t = threadIdx.x;
    const int row0 = blockIdx.x * 128;
    const int rg = t >> 3;
    const int f0 = (t & 7) * 8;

    float acc[4][8];
#pragma unroll
    for (int j = 0; j < 4; j++)
#pragma unroll
        for (int c = 0; c < 8; c++) acc[j][c] = 0.0f;

    for (int kc = 0; kc < K; kc += 64) {
        __syncthreads();
        const float4* Wg = (const float4*)(W + (size_t)kc * 64);
        float4* ws4 = (float4*)ws;
#pragma unroll
        for (int i = 0; i < 4; i++) ws4[t + i * 256] = Wg[t + i * 256];
#pragma unroll
        for (int p = 0; p < 8; p++) {
            int rr = p * 16 + (t >> 4);
            int c4 = (t & 15) * 4;
            int row = row0 + rr;
            float4 v = make_float4(0.f, 0.f, 0.f, 0.f);
            if (row < M) v = *(const float4*)(X + (size_t)row * K + kc + c4);
            *(float4*)(&xs[rr * 68 + c4]) = v;
        }
        __syncthreads();

        for (int kk = 0; kk < 64; kk += 4) {
            float4 xv[4];
#pragma unroll
            for (int j = 0; j < 4; j++)
                xv[j] = *(const float4*)(&xs[(rg + 32 * j) * 68 + kk]);
#pragma unroll
            for (int kki = 0; kki < 4; kki++) {
                float4 w0 = *(const float4*)(&ws[(kk + kki) * 64 + f0]);
                float4 w1 = *(const float4*)(&ws[(kk + kki) * 64 + f0 + 4]);
#pragma unroll
                for (int j = 0; j < 4; j++) {
                    float a = (&xv[j].x)[kki];
                    acc[j][0] = fmaf(a, w0.x, acc[j][0]);
                    acc[j][1] = fmaf(a, w0.y, acc[j][1]);
                    acc[j][2] = fmaf(a, w0.z, acc[j][2]);
                    acc[j][3] = fmaf(a, w0.w, acc[j][3]);
                    acc[j][4] = fmaf(a, w1.x, acc[j][4]);
                    acc[j][5] = fmaf(a, w1.y, acc[j][5]);
                    acc[j][6] = fmaf(a, w1.z, acc[j][6]);
                    acc[j][7] = fmaf(a, w1.w, acc[j][7]);
                }
            }
        }
    }

    const int slice = f0 >> 4;   // which 16-feature slice
    const int rem = f0 & 15;     // 0 or 8 feats within the slice
#pragma unroll
    for (int j = 0; j < 4; j++) {
        int row = row0 + rg + 32 * j;
        if (row < M) {
            float di = dinv[row];
            uint4 pk;
            pk.x = (u32)f2bf(acc[j][0] * di) | ((u32)f2bf(acc[j][1] * di) << 16);
            pk.y = (u32)f2bf(acc[j][2] * di) | ((u32)f2bf(acc[j][3] * di) << 16);
            pk.z = (u32)f2bf(acc[j][4] * di) | ((u32)f2bf(acc[j][5] * di) << 16);
            pk.w = (u32)f2bf(acc[j][6] * di) | ((u32)f2bf(acc[j][7] * di) << 16);
            *(uint4*)(hp + ((size_t)slice * (NN + 1) + row) * 16 + rem) = pk;
        }
    }
}

// ===== aggregation: slice bound to XCD pair via blockIdx%8 (spatial L2 residency) =====
// slice = (b&7)>>1 -> each XCD only ever gathers from ONE 3.2MB slice (fits 4MB L2,
// permanently resident). 8 nodes/wave amortize meta/params; 8 rec loads issued
// up-front for cross-node MLP; 8 lanes/edge (32B slice row), 8 edges per gather instr.
__device__ __forceinline__ u32 load_rec(int k, const int* __restrict__ esf,
                                        int beg8, int mp8, int lane) {
    int mpk = __shfl(mp8, k);
    int begk = __shfl(beg8, k);
    int mm = mpk < 64 ? mpk : 64;
    return (lane < mm) ? (u32)esf[begk + lane] : (u32)NN;
}

__device__ __forceinline__ void gather_node(int k, u32 rk, const u32* __restrict__ hs,
                                            const int* __restrict__ esf, int beg8, int mp8,
                                            u32 sv, int lane, int g8, int fp,
                                            float& A0, float& A1) {
    int mpk = __shfl(mp8, k);
    int mm = mpk < 64 ? mpk : 64;
    for (int j = 0; j < mm; j += 8) {           // sentinel-padded rec -> safe overshoot
        int s = __shfl((int)rk, j + g8);
        u32 v = hs[s * SLICE_U32 + fp];
        A0 += __uint_as_float(v << 16);
        A1 += __uint_as_float(v & 0xFFFF0000u);
    }
    if (mpk > 64) {                              // rare deep-degree path
        int begk = __shfl(beg8, k);
        for (int c = 64; c < mpk; c += 64) {
            int m2 = mpk - c; if (m2 > 64) m2 = 64;
            int rr = (lane < m2) ? esf[begk + c + lane] : NN;
            for (int j = 0; j < m2; j += 8) {
                int s = __shfl(rr, j + g8);
                u32 v = hs[s * SLICE_U32 + fp];
                A0 += __uint_as_float(v << 16);
                A1 += __uint_as_float(v & 0xFFFF0000u);
            }
        }
    }
    if (g8 == k) {                               // self-loop row, counted once
        A0 += __uint_as_float(sv << 16);
        A1 += __uint_as_float(sv & 0xFFFF0000u);
    }
}

__device__ __forceinline__ void finish_node(int k, float A0, float A1, float di8,
                                            float bix, float biy, float rmex, float rmey,
                                            float scx, float scy, float bex, float bey,
                                            int g8, int f0, int n0, float* __restrict__ out) {
    A0 += __shfl_xor(A0, 8);  A1 += __shfl_xor(A1, 8);
    A0 += __shfl_xor(A0, 16); A1 += __shfl_xor(A1, 16);
    A0 += __shfl_xor(A0, 32); A1 += __shfl_xor(A1, 32);
    float dik = __shfl(di8, k);
    float yx = (A0 * dik + bix - rmex) * scx + bex;
    float yy = (A1 * dik + biy - rmey) * scy + bey;
    if (g8 == 0)
        *(float2*)(out + (size_t)(n0 + k) * 64 + f0) =
            make_float2(fmaxf(yx, 0.0f), fmaxf(yy, 0.0f));
}

__global__ __launch_bounds__(256) void k_agg(const u32* __restrict__ hp,
                                             const int* __restrict__ esf,
                                             const int* __restrict__ offs,
                                             const int* __restrict__ cntp,
                                             const float* __restrict__ dinv,
                                             const float* __restrict__ bias,
                                             const float* __restrict__ gam,
                                             const float* __restrict__ bet,
                                             const float* __restrict__ rm,
                                             const float* __restrict__ rv,
                                             float* __restrict__ out) {
    const int b = blockIdx.x;
    const int slice = (b & 7) >> 1;                 // XCD-bound slice
    const int i = ((b >> 3) << 1) | (b & 1);        // node-group within slice
    const int wv = threadIdx.x >> 6;
    const int lane = threadIdx.x & 63;
    const int g8 = lane >> 3;                       // edge slot within a batch of 8
    const int fp = lane & 7;                        // u32 word within 32B row-slice
    const int n0 = i * 32 + wv * 8;                 // 8 consecutive nodes (never cross a 128-bucket)
    if (n0 >= NN) return;
    const u32* hs = hp + (size_t)slice * (NN + 1) * SLICE_U32;

    // meta for 8 nodes in lanes 0..7
    int beg8 = 0, mp8 = 0; float di8 = 0.0f;
    if (lane < 8) {
        beg8 = offs[n0 + lane];
        mp8 = cntp[n0 + lane];
        di8 = dinv[n0 + lane];
    }
    // self rows: node n0+g8, word fp (one load covers all 8 nodes)
    u32 sv = hs[(n0 + g8) * SLICE_U32 + fp];

    // per-slice BN params (shared by all 8 nodes)
    const int f0 = slice * 16 + fp * 2;
    float2 bi  = *(const float2*)(bias + f0);
    float2 ga  = *(const float2*)(gam + f0);
    float2 be  = *(const float2*)(bet + f0);
    float2 rme = *(const float2*)(rm + f0);
    float2 rva = *(const float2*)(rv + f0);
    float scx = ga.x * rsqrtf(rva.x + BN_EPS);
    float scy = ga.y * rsqrtf(rva.y + BN_EPS);

    // phase 1: issue all 8 edge-record loads (cross-node MLP)
    u32 r0 = load_rec(0, esf, beg8, mp8, lane);
    u32 r1 = load_rec(1, esf, beg8, mp8, lane);
    u32 r2 = load_rec(2, esf, beg8, mp8, lane);
    u32 r3 = load_rec(3, esf, beg8, mp8, lane);
    u32 r4 = load_rec(4, esf, beg8, mp8, lane);
    u32 r5 = load_rec(5, esf, beg8, mp8, lane);
    u32 r6 = load_rec(6, esf, beg8, mp8, lane);
    u32 r7 = load_rec(7, esf, beg8, mp8, lane);

    float a00 = 0.f, a01 = 0.f, a10 = 0.f, a11 = 0.f, a20 = 0.f, a21 = 0.f, a30 = 0.f, a31 = 0.f;
    float a40 = 0.f, a41 = 0.f, a50 = 0.f, a51 = 0.f, a60 = 0.f, a61 = 0.f, a70 = 0.f, a71 = 0.f;

    // phase 2: gather per node (L2-resident slice)
    gather_node(0, r0, hs, esf, beg8, mp8, sv, lane, g8, fp, a00, a01);
    gather_node(1, r1, hs, esf, beg8, mp8, sv, lane, g8, fp, a10, a11);
    gather_node(2, r2, hs, esf, beg8, mp8, sv, lane, g8, fp, a20, a21);
    gather_node(3, r3, hs, esf, beg8, mp8, sv, lane, g8, fp, a30, a31);
    gather_node(4, r4, hs, esf, beg8, mp8, sv, lane, g8, fp, a40, a41);
    gather_node(5, r5, hs, esf, beg8, mp8, sv, lane, g8, fp, a50, a51);
    gather_node(6, r6, hs, esf, beg8, mp8, sv, lane, g8, fp, a60, a61);
    gather_node(7, r7, hs, esf, beg8, mp8, sv, lane, g8, fp, a70, a71);

    // phase 3: butterfly + BN + ReLU + store per node
    finish_node(0, a00, a01, di8, bi.x, bi.y, rme.x, rme.y, scx, scy, be.x, be.y, g8, f0, n0, out);
    finish_node(1, a10, a11, di8, bi.x, bi.y, rme.x, rme.y, scx, scy, be.x, be.y, g8, f0, n0, out);
    finish_node(2, a20, a21, di8, bi.x, bi.y, rme.x, rme.y, scx, scy, be.x, be.y, g8, f0, n0, out);
    finish_node(3, a30, a31, di8, bi.x, bi.y, rme.x, rme.y, scx, scy, be.x, be.y, g8, f0, n0, out);
    finish_node(4, a40, a41, di8, bi.x, bi.y, rme.x, rme.y, scx, scy, be.x, be.y, g8, f0, n0, out);
    finish_node(5, a50, a51, di8, bi.x, bi.y, rme.x, rme.y, scx, scy, be.x, be.y, g8, f0, n0, out);
    finish_node(6, a60, a61, di8, bi.x, bi.y, rme.x, rme.y, scx, scy, be.x, be.y, g8, f0, n0, out);
    finish_node(7, a70, a71, di8, bi.x, bi.y, rme.x, rme.y, scx, scy, be.x, be.y, g8, f0, n0, out);
}

// ===== fused mean-pool + classifier: one block per graph, batch sorted, no atomics =====
__global__ __launch_bounds__(256) void k_poolcls(const float* __restrict__ h,
                                                 const int* __restrict__ batch,
                                                 const float* __restrict__ Wc,
                                                 const float* __restrict__ bc,
                                                 float* __restrict__ out) {
    __shared__ float sh[256];
    const int g = blockIdx.x;
    const int t = threadIdx.x;
    const int lane = t & 63;
    const int wv = t >> 6;
    int lo = 0, hi = NN;
    while (lo < hi) { int mid = (lo + hi) >> 1; if (batch[mid] < g) lo = mid + 1; else hi = mid; }
    const int r0 = lo;
    hi = NN;
    while (lo < hi) { int mid = (lo + hi) >> 1; if (batch[mid] < g + 1) lo = mid + 1; else hi = mid; }
    const int r1 = lo;
    float acc = 0.0f;
    for (int r = r0 + wv; r < r1; r += 4)
        acc += h[(size_t)r * 64 + lane];
    sh[t] = acc;
    __syncthreads();
    if (wv == 0) {
        float p = sh[lane] + sh[64 + lane] + sh[128 + lane] + sh[192 + lane];
        p *= 1.0f / fmaxf((float)(r1 - r0), 1.0f);
        float c0 = p * Wc[lane * 3 + 0];
        float c1 = p * Wc[lane * 3 + 1];
        float c2 = p * Wc[lane * 3 + 2];
        for (int o = 32; o > 0; o >>= 1) {
            c0 += __shfl_xor(c0, o);
            c1 += __shfl_xor(c1, o);
            c2 += __shfl_xor(c2, o);
        }
        if (lane == 0) {
            out[g * 3 + 0] = c0 + bc[0];
            out[g * 3 + 1] = c1 + bc[1];
            out[g * 3 + 2] = c2 + bc[2];
        }
    }
}

extern "C" void kernel_launch(void* const* d_in, const int* in_sizes, int n_in,
                              void* d_out, int out_size, void* d_ws, size_t ws_size,
                              hipStream_t stream) {
    const float* x   = (const float*)d_in[0];
    const float* W1  = (const float*)d_in[1];
    const float* b1  = (const float*)d_in[2];
    const float* g1  = (const float*)d_in[3];
    const float* bt1 = (const float*)d_in[4];
    const float* rm1 = (const float*)d_in[5];
    const float* rv1 = (const float*)d_in[6];
    const float* W2  = (const float*)d_in[7];
    const float* b2  = (const float*)d_in[8];
    const float* g2  = (const float*)d_in[9];
    const float* bt2 = (const float*)d_in[10];
    const float* rm2 = (const float*)d_in[11];
    const float* rv2 = (const float*)d_in[12];
    const float* Wc  = (const float*)d_in[13];
    const float* bc  = (const float*)d_in[14];
    const int* ei    = (const int*)d_in[15];
    const int* batch = (const int*)d_in[16];
    const int* srcp = ei;
    const int* dstp = ei + NE;

    char* ws = (char*)d_ws;
    u16*   hpb    = (u16*)(ws);                 // 4 slices x (NN+1)*16 bf16 = 12,800,128 B
    int*   ccount = (int*)(ws + 12800128);      // NCB
    int*   cbase  = (int*)(ws + 12803264);      // NCB+1
    int*   fbase  = (int*)(ws + 12806400);      // NCB
    int*   gcur   = (int*)(ws + 12809536);      // NCB
    int*   offs   = (int*)(ws + 12812672);      // NN
    int*   cntp   = (int*)(ws + 13212672);      // NN
    float* dinv   = (float*)(ws + 13612672);    // NN
    int*   esf    = (int*)(ws + 14012672);      // NE + 387*NCB ints (~14.0 MB)
    float* bufB   = (float*)(ws + 28052672);    // NN*64 fp32 = 25.6 MB
    int*   esc    = (int*)(ws + 28052672);      // NE ints — overlaps bufB (dead before agg1 writes)

    // ---- init: ccount zeroed; per-slice sentinel rows zeroed inside k_cscan ----
    hipMemsetAsync(ccount, 0, NCB * 4, stream);

    // ---- CSR build ----
    k_chist<<<512, 256, 0, stream>>>(dstp, ccount);
    k_cscan<<<1, 256, 0, stream>>>(ccount, cbase, fbase, gcur, (u32*)hpb);
    k_p1<<<(NE + P1_CHUNK - 1) / P1_CHUNK, 1024, 0, stream>>>(srcp, dstp, gcur, esc);
    k_p2<<<NCB, 256, 0, stream>>>(esc, cbase, fbase, esf, offs, cntp, dinv);

    // ---- layer 1 ----
    k_gemm<128><<<(NN + 127) / 128, 256, 0, stream>>>(x, W1, dinv, hpb, NN);
    k_agg<<<AGG_GRID, 256, 0, stream>>>((const u32*)hpb, esf, offs, cntp, dinv, b1, g1, bt1, rm1, rv1, bufB);

    // ---- layer 2 ----
    k_gemm<64><<<(NN + 127) / 128, 256, 0, stream>>>(bufB, W2, dinv, hpb, NN);
    k_agg<<<AGG_GRID, 256, 0, stream>>>((const u32*)hpb, esf, offs, cntp, dinv, b2, g2, bt2, rm2, rv2, bufB);

    // ---- fused mean-pool + classify ----
    k_poolcls<<<NG, 256, 0, stream>>>(bufB, batch, Wc, bc, (float*)d_out);
}

// Round 6
// 435.408 us; speedup vs baseline: 1.1107x; 1.1107x over previous
//
#include <hip/hip_runtime.h>

#define NN 100000
#define NE 3200000
#define NG 512
#define NCB 782           // coarse buckets of 128 nodes: ceil(100000/128)
#define BN_EPS 1e-5f
#define NSLICE 4          // feature slices: 16 feats = 32B per row-slice
#define SLICE_U32 8       // u32 words per row-slice
#define AGG_GRID 12504    // 1563*8: slice = (b&7)>>1 (XCD-bound), 3126 node-groups/slice

typedef unsigned short u16;
typedef unsigned int u32;

__device__ __forceinline__ u16 f2bf(float f) {
    u32 u = __float_as_uint(f);
    u += 0x7FFF + ((u >> 16) & 1);  // RNE
    return (u16)(u >> 16);
}

// ================= coarse histogram (LDS-privatized) =================
__global__ __launch_bounds__(256) void k_chist(const int* __restrict__ dst, int* __restrict__ ccount) {
    __shared__ int h[NCB];
    int t = threadIdx.x;
    for (int i = t; i < NCB; i += 256) h[i] = 0;
    __syncthreads();
    int stride = gridDim.x * 256;
    for (int e = blockIdx.x * 256 + t; e < NE; e += stride)
        atomicAdd(&h[dst[e] >> 7], 1);
    __syncthreads();
    for (int i = t; i < NCB; i += 256)
        if (h[i]) atomicAdd(&ccount[i], h[i]);
}

// ========== scan coarse counts -> cbase, padded fine bases, global cursors ==========
// also zeroes the 4 per-slice sentinel rows of hp (row NN of each slice)
__global__ __launch_bounds__(256) void k_cscan(const int* __restrict__ ccount, int* __restrict__ cbase,
                                               int* __restrict__ fbase, int* __restrict__ gcur,
                                               u32* __restrict__ hpz) {
    __shared__ int sh[256], sh2[256];
    int t = threadIdx.x;
    if (t < NSLICE * SLICE_U32) {
        int slice = t >> 3, w = t & 7;
        hpz[(size_t)slice * (NN + 1) * SLICE_U32 + (size_t)NN * SLICE_U32 + w] = 0;
    }
    int v[4], w[4];
    int s = 0, s2 = 0;
#pragma unroll
    for (int j = 0; j < 4; j++) {
        int idx = t * 4 + j;
        int c = (idx < NCB) ? ccount[idx] : 0;
        v[j] = c;
        w[j] = (idx < NCB) ? ((c + 387) & ~3) : 0;  // <=3 pad per node * 128 nodes, x4 aligned
        s += v[j]; s2 += w[j];
    }
    sh[t] = s; sh2[t] = s2;
    __syncthreads();
    for (int off = 1; off < 256; off <<= 1) {
        int x = (t >= off) ? sh[t - off] : 0;
        int x2 = (t >= off) ? sh2[t - off] : 0;
        __syncthreads();
        sh[t] += x; sh2[t] += x2;
        __syncthreads();
    }
    int run = sh[t] - s, run2 = sh2[t] - s2;
#pragma unroll
    for (int j = 0; j < 4; j++) {
        int idx = t * 4 + j;
        if (idx < NCB) { cbase[idx] = run; gcur[idx] = run; fbase[idx] = run2; }
        run += v[j]; run2 += w[j];
    }
    if (t == 255) cbase[NCB] = run;  // == NE
}

// ========== pass 1: coarse binning ==========
#define P1_CHUNK 16384
__global__ __launch_bounds__(1024) void k_p1(const int* __restrict__ src, const int* __restrict__ dst,
                                             int* __restrict__ gcur, int* __restrict__ esc) {
    __shared__ int ccur[NCB];
    const int t = threadIdx.x;
    const int e0 = blockIdx.x * P1_CHUNK;
    for (int i = t; i < NCB; i += 1024) ccur[i] = 0;
    __syncthreads();
    int n = NE - e0; if (n > P1_CHUNK) n = P1_CHUNK;
    // phase 1: block-local histogram
    for (int idx = t; idx < n; idx += 1024)
        atomicAdd(&ccur[dst[e0 + idx] >> 7], 1);
    __syncthreads();
    // phase 2: one global reservation per (block,bucket)
    for (int i = t; i < NCB; i += 1024) {
        int c = ccur[i];
        ccur[i] = (c > 0) ? atomicAdd(&gcur[i], c) : 0;
    }
    __syncthreads();
    // phase 3: scatter (re-read src/dst — L3-hot)
    for (int idx = t; idx < n; idx += 1024) {
        int dd = dst[e0 + idx];
        int s = src[e0 + idx];
        int pos = atomicAdd(&ccur[dd >> 7], 1);
        esc[pos] = s | ((dd & 127) << 17);  // 17b src | 7b dstLocal
    }
}

// ========== pass 2: fine per-node CSR within each coarse bucket; emits offs/cntp/dinv ==========
__global__ __launch_bounds__(256) void k_p2(const int* __restrict__ esc, const int* __restrict__ cbase,
                                            const int* __restrict__ fbase, int* __restrict__ esf,
                                            int* __restrict__ offs, int* __restrict__ cntp,
                                            float* __restrict__ dinv) {
    __shared__ int lcnt[128], loff[128], lcur[128];
    int t = threadIdx.x, b = blockIdx.x;
    int c0 = cbase[b], c1 = cbase[b + 1];
    if (t < 128) lcnt[t] = 0;
    __syncthreads();
    for (int i = c0 + t; i < c1; i += 256) atomicAdd(&lcnt[esc[i] >> 17], 1);
    __syncthreads();
    int p = 0, cnt = 0;
    if (t < 128) { cnt = lcnt[t]; p = (cnt + 3) & ~3; loff[t] = p; }
    __syncthreads();
    for (int off = 1; off < 128; off <<= 1) {
        int x = (t >= off && t < 128) ? loff[t - off] : 0;
        __syncthreads();
        if (t < 128) loff[t] += x;
        __syncthreads();
    }
    int fb = fbase[b];
    int node = (b << 7) + t;
    if (t < 128) {
        int o = fb + loff[t] - p;
        lcur[t] = o;
        if (node < NN) {
            offs[node] = o;
            cntp[node] = p;
            dinv[node] = rsqrtf((float)(cnt + 1));  // +1 self-loop
            for (int q = cnt; q < p; q++) esf[o + q] = NN;  // sentinel -> zero row
        }
    }
    __syncthreads();
    for (int i = c0 + t; i < c1; i += 256) {
        int rec = esc[i];
        int pos = atomicAdd(&lcur[rec >> 17], 1);
        esf[pos] = rec & 0x1FFFF;
    }
}

// ===== GEMM: hp_s[slice][M][16] = bf16( (X[M][K] @ W[K][64]) * dinv[row] ), feature-sliced =====
template <int K>
__global__ __launch_bounds__(256) void k_gemm(const float* __restrict__ X,
                                              const float* __restrict__ W,
                                              const float* __restrict__ dinv,
                                              u16* __restrict__ hp, int M) {
    __shared__ float xs[128 * 68];
    __shared__ float ws[64 * 64];
    const int t = threadIdx.x;
    const int row0 = blockIdx.x * 128;
    const int rg = t >> 3;
    const int f0 = (t & 7) * 8;

    float acc[4][8];
#pragma unroll
    for (int j = 0; j < 4; j++)
#pragma unroll
        for (int c = 0; c < 8; c++) acc[j][c] = 0.0f;

    for (int kc = 0; kc < K; kc += 64) {
        __syncthreads();
        const float4* Wg = (const float4*)(W + (size_t)kc * 64);
        float4* ws4 = (float4*)ws;
#pragma unroll
        for (int i = 0; i < 4; i++) ws4[t + i * 256] = Wg[t + i * 256];
#pragma unroll
        for (int p = 0; p < 8; p++) {
            int rr = p * 16 + (t >> 4);
            int c4 = (t & 15) * 4;
            int row = row0 + rr;
            float4 v = make_float4(0.f, 0.f, 0.f, 0.f);
            if (row < M) v = *(const float4*)(X + (size_t)row * K + kc + c4);
            *(float4*)(&xs[rr * 68 + c4]) = v;
        }
        __syncthreads();

        for (int kk = 0; kk < 64; kk += 4) {
            float4 xv[4];
#pragma unroll
            for (int j = 0; j < 4; j++)
                xv[j] = *(const float4*)(&xs[(rg + 32 * j) * 68 + kk]);
#pragma unroll
            for (int kki = 0; kki < 4; kki++) {
                float4 w0 = *(const float4*)(&ws[(kk + kki) * 64 + f0]);
                float4 w1 = *(const float4*)(&ws[(kk + kki) * 64 + f0 + 4]);
#pragma unroll
                for (int j = 0; j < 4; j++) {
                    float a = (&xv[j].x)[kki];
                    acc[j][0] = fmaf(a, w0.x, acc[j][0]);
                    acc[j][1] = fmaf(a, w0.y, acc[j][1]);
                    acc[j][2] = fmaf(a, w0.z, acc[j][2]);
                    acc[j][3] = fmaf(a, w0.w, acc[j][3]);
                    acc[j][4] = fmaf(a, w1.x, acc[j][4]);
                    acc[j][5] = fmaf(a, w1.y, acc[j][5]);
                    acc[j][6] = fmaf(a, w1.z, acc[j][6]);
                    acc[j][7] = fmaf(a, w1.w, acc[j][7]);
                }
            }
        }
    }

    const int slice = f0 >> 4;   // which 16-feature slice
    const int rem = f0 & 15;     // 0 or 8 feats within the slice
#pragma unroll
    for (int j = 0; j < 4; j++) {
        int row = row0 + rg + 32 * j;
        if (row < M) {
            float di = dinv[row];
            uint4 pk;
            pk.x = (u32)f2bf(acc[j][0] * di) | ((u32)f2bf(acc[j][1] * di) << 16);
            pk.y = (u32)f2bf(acc[j][2] * di) | ((u32)f2bf(acc[j][3] * di) << 16);
            pk.z = (u32)f2bf(acc[j][4] * di) | ((u32)f2bf(acc[j][5] * di) << 16);
            pk.w = (u32)f2bf(acc[j][6] * di) | ((u32)f2bf(acc[j][7] * di) << 16);
            *(uint4*)(hp + ((size_t)slice * (NN + 1) + row) * 16 + rem) = pk;
        }
    }
}

// ===== aggregation v6: XCD-bound slice (R5, proven FETCH 162->68MB) + round-major
// software-pipelined gathers (restores 8-16 outstanding requests, R5's serial-chain fix).
// 8 nodes/wave; round r issues 8 independent loads (one per node, fully unrolled);
// round r+1 issued before round r is consumed. Rounds 0-3 unconditional (sentinel-safe:
// rec lanes >= deg hold NN -> L2-hot zero row), rounds 4-7 guarded by wave-max degree.
__device__ __forceinline__ u32 load_rec(int k, const int* __restrict__ esf,
                                        int beg8, int mp8, int lane) {
    int mpk = __shfl(mp8, k);
    int begk = __shfl(beg8, k);
    int mm = mpk < 64 ? mpk : 64;
    return (lane < mm) ? (u32)esf[begk + lane] : (u32)NN;
}

#define ISSUE(r, B) do { \
    int s_; \
    s_ = __shfl(rc0, (r) * 8 + g8); B##0 = hsf[(size_t)s_ * SLICE_U32]; \
    s_ = __shfl(rc1, (r) * 8 + g8); B##1 = hsf[(size_t)s_ * SLICE_U32]; \
    s_ = __shfl(rc2, (r) * 8 + g8); B##2 = hsf[(size_t)s_ * SLICE_U32]; \
    s_ = __shfl(rc3, (r) * 8 + g8); B##3 = hsf[(size_t)s_ * SLICE_U32]; \
    s_ = __shfl(rc4, (r) * 8 + g8); B##4 = hsf[(size_t)s_ * SLICE_U32]; \
    s_ = __shfl(rc5, (r) * 8 + g8); B##5 = hsf[(size_t)s_ * SLICE_U32]; \
    s_ = __shfl(rc6, (r) * 8 + g8); B##6 = hsf[(size_t)s_ * SLICE_U32]; \
    s_ = __shfl(rc7, (r) * 8 + g8); B##7 = hsf[(size_t)s_ * SLICE_U32]; \
} while (0)

#define CONSUME(B) do { \
    a00 += __uint_as_float(B##0 << 16); a01 += __uint_as_float(B##0 & 0xFFFF0000u); \
    a10 += __uint_as_float(B##1 << 16); a11 += __uint_as_float(B##1 & 0xFFFF0000u); \
    a20 += __uint_as_float(B##2 << 16); a21 += __uint_as_float(B##2 & 0xFFFF0000u); \
    a30 += __uint_as_float(B##3 << 16); a31 += __uint_as_float(B##3 & 0xFFFF0000u); \
    a40 += __uint_as_float(B##4 << 16); a41 += __uint_as_float(B##4 & 0xFFFF0000u); \
    a50 += __uint_as_float(B##5 << 16); a51 += __uint_as_float(B##5 & 0xFFFF0000u); \
    a60 += __uint_as_float(B##6 << 16); a61 += __uint_as_float(B##6 & 0xFFFF0000u); \
    a70 += __uint_as_float(B##7 << 16); a71 += __uint_as_float(B##7 & 0xFFFF0000u); \
} while (0)

#define DEEP(k, A0, A1) do { \
    int mpk_ = __shfl(mp8, k); \
    if (mpk_ > 64) { \
        int begk_ = __shfl(beg8, k); \
        for (int c_ = 64; c_ < mpk_; c_ += 64) { \
            int m2_ = mpk_ - c_; if (m2_ > 64) m2_ = 64; \
            int rr_ = (lane < m2_) ? esf[begk_ + c_ + lane] : NN; \
            for (int j_ = 0; j_ < m2_; j_ += 8) { \
                int s_ = __shfl(rr_, j_ + g8); \
                u32 v_ = hsf[(size_t)s_ * SLICE_U32]; \
                A0 += __uint_as_float(v_ << 16); \
                A1 += __uint_as_float(v_ & 0xFFFF0000u); \
            } \
        } \
    } \
} while (0)

__device__ __forceinline__ void finish_node(int k, float A0, float A1, float di8,
                                            float bix, float biy, float rmex, float rmey,
                                            float scx, float scy, float bex, float bey,
                                            int g8, int f0, int n0, float* __restrict__ out) {
    A0 += __shfl_xor(A0, 8);  A1 += __shfl_xor(A1, 8);
    A0 += __shfl_xor(A0, 16); A1 += __shfl_xor(A1, 16);
    A0 += __shfl_xor(A0, 32); A1 += __shfl_xor(A1, 32);
    float dik = __shfl(di8, k);
    float yx = (A0 * dik + bix - rmex) * scx + bex;
    float yy = (A1 * dik + biy - rmey) * scy + bey;
    if (g8 == 0)
        *(float2*)(out + (size_t)(n0 + k) * 64 + f0) =
            make_float2(fmaxf(yx, 0.0f), fmaxf(yy, 0.0f));
}

__global__ __launch_bounds__(256) void k_agg(const u32* __restrict__ hp,
                                             const int* __restrict__ esf,
                                             const int* __restrict__ offs,
                                             const int* __restrict__ cntp,
                                             const float* __restrict__ dinv,
                                             const float* __restrict__ bias,
                                             const float* __restrict__ gam,
                                             const float* __restrict__ bet,
                                             const float* __restrict__ rm,
                                             const float* __restrict__ rv,
                                             float* __restrict__ out) {
    const int b = blockIdx.x;
    const int slice = (b & 7) >> 1;                 // XCD-bound slice
    const int i = ((b >> 3) << 1) | (b & 1);        // node-group within slice
    const int wv = threadIdx.x >> 6;
    const int lane = threadIdx.x & 63;
    const int g8 = lane >> 3;                       // edge slot within a batch of 8
    const int fp = lane & 7;                        // u32 word within 32B row-slice
    const int n0 = i * 32 + wv * 8;                 // 8 consecutive nodes
    if (n0 >= NN) return;
    const u32* hsf = hp + (size_t)slice * (NN + 1) * SLICE_U32 + fp;

    // meta for 8 nodes in lanes 0..7
    int beg8 = 0, mp8 = 0; float di8 = 0.0f;
    if (lane < 8) {
        beg8 = offs[n0 + lane];
        mp8 = cntp[n0 + lane];
        di8 = dinv[n0 + lane];
    }
    // self rows: node n0+g8, word fp (one load covers all 8 nodes)
    u32 sv = hsf[(size_t)(n0 + g8) * SLICE_U32];

    // wave-max degree (lanes 0..7 hold mp8; reduce over 8, broadcast)
    int mx = (lane < 8) ? mp8 : 0;
    mx = max(mx, __shfl_xor(mx, 1));
    mx = max(mx, __shfl_xor(mx, 2));
    mx = max(mx, __shfl_xor(mx, 4));
    const int mpmax = __shfl(mx, 0);

    // per-slice BN params (shared by all 8 nodes)
    const int f0 = slice * 16 + fp * 2;
    float2 bi  = *(const float2*)(bias + f0);
    float2 ga  = *(const float2*)(gam + f0);
    float2 be  = *(const float2*)(bet + f0);
    float2 rme = *(const float2*)(rm + f0);
    float2 rva = *(const float2*)(rv + f0);
    float scx = ga.x * rsqrtf(rva.x + BN_EPS);
    float scy = ga.y * rsqrtf(rva.y + BN_EPS);

    // edge records for all 8 nodes (8 independent esf loads in flight)
    int rc0 = (int)load_rec(0, esf, beg8, mp8, lane);
    int rc1 = (int)load_rec(1, esf, beg8, mp8, lane);
    int rc2 = (int)load_rec(2, esf, beg8, mp8, lane);
    int rc3 = (int)load_rec(3, esf, beg8, mp8, lane);
    int rc4 = (int)load_rec(4, esf, beg8, mp8, lane);
    int rc5 = (int)load_rec(5, esf, beg8, mp8, lane);
    int rc6 = (int)load_rec(6, esf, beg8, mp8, lane);
    int rc7 = (int)load_rec(7, esf, beg8, mp8, lane);

    float a00 = 0.f, a01 = 0.f, a10 = 0.f, a11 = 0.f, a20 = 0.f, a21 = 0.f, a30 = 0.f, a31 = 0.f;
    float a40 = 0.f, a41 = 0.f, a50 = 0.f, a51 = 0.f, a60 = 0.f, a61 = 0.f, a70 = 0.f, a71 = 0.f;

    u32 x0, x1, x2, x3, x4, x5, x6, x7;   // staging buffer A
    u32 y0, y1, y2, y3, y4, y5, y6, y7;   // staging buffer B

    // pipelined round-major gather: issue round r+1 before consuming round r
    ISSUE(0, x);
    ISSUE(1, y); CONSUME(x);              // round 0 consumed; round 1 in flight
    ISSUE(2, x); CONSUME(y);              // round 1
    ISSUE(3, y); CONSUME(x);              // round 2
    const bool b4 = mpmax > 32, b5 = mpmax > 40, b6 = mpmax > 48, b7 = mpmax > 56;
    if (b4) { ISSUE(4, x); }
    CONSUME(y);                           // round 3
    if (b4) { if (b5) { ISSUE(5, y); } CONSUME(x); }   // round 4
    if (b5) { if (b6) { ISSUE(6, x); } CONSUME(y); }   // round 5
    if (b6) { if (b7) { ISSUE(7, y); } CONSUME(x); }   // round 6
    if (b7) { CONSUME(y); }                            // round 7

    // self-loop rows (counted exactly once per node)
    float svx = __uint_as_float(sv << 16), svy = __uint_as_float(sv & 0xFFFF0000u);
    if (g8 == 0) { a00 += svx; a01 += svy; }
    if (g8 == 1) { a10 += svx; a11 += svy; }
    if (g8 == 2) { a20 += svx; a21 += svy; }
    if (g8 == 3) { a30 += svx; a31 += svy; }
    if (g8 == 4) { a40 += svx; a41 += svy; }
    if (g8 == 5) { a50 += svx; a51 += svy; }
    if (g8 == 6) { a60 += svx; a61 += svy; }
    if (g8 == 7) { a70 += svx; a71 += svy; }

    // deep-degree correctness path (deg > 64; essentially never for Poisson(32))
    if (mpmax > 64) {
        DEEP(0, a00, a01); DEEP(1, a10, a11); DEEP(2, a20, a21); DEEP(3, a30, a31);
        DEEP(4, a40, a41); DEEP(5, a50, a51); DEEP(6, a60, a61); DEEP(7, a70, a71);
    }

    // butterfly + BN + ReLU + store per node
    finish_node(0, a00, a01, di8, bi.x, bi.y, rme.x, rme.y, scx, scy, be.x, be.y, g8, f0, n0, out);
    finish_node(1, a10, a11, di8, bi.x, bi.y, rme.x, rme.y, scx, scy, be.x, be.y, g8, f0, n0, out);
    finish_node(2, a20, a21, di8, bi.x, bi.y, rme.x, rme.y, scx, scy, be.x, be.y, g8, f0, n0, out);
    finish_node(3, a30, a31, di8, bi.x, bi.y, rme.x, rme.y, scx, scy, be.x, be.y, g8, f0, n0, out);
    finish_node(4, a40, a41, di8, bi.x, bi.y, rme.x, rme.y, scx, scy, be.x, be.y, g8, f0, n0, out);
    finish_node(5, a50, a51, di8, bi.x, bi.y, rme.x, rme.y, scx, scy, be.x, be.y, g8, f0, n0, out);
    finish_node(6, a60, a61, di8, bi.x, bi.y, rme.x, rme.y, scx, scy, be.x, be.y, g8, f0, n0, out);
    finish_node(7, a70, a71, di8, bi.x, bi.y, rme.x, rme.y, scx, scy, be.x, be.y, g8, f0, n0, out);
}

// ===== fused mean-pool + classifier: one block per graph, batch sorted, no atomics =====
__global__ __launch_bounds__(256) void k_poolcls(const float* __restrict__ h,
                                                 const int* __restrict__ batch,
                                                 const float* __restrict__ Wc,
                                                 const float* __restrict__ bc,
                                                 float* __restrict__ out) {
    __shared__ float sh[256];
    const int g = blockIdx.x;
    const int t = threadIdx.x;
    const int lane = t & 63;
    const int wv = t >> 6;
    int lo = 0, hi = NN;
    while (lo < hi) { int mid = (lo + hi) >> 1; if (batch[mid] < g) lo = mid + 1; else hi = mid; }
    const int r0 = lo;
    hi = NN;
    while (lo < hi) { int mid = (lo + hi) >> 1; if (batch[mid] < g + 1) lo = mid + 1; else hi = mid; }
    const int r1 = lo;
    float acc = 0.0f;
    for (int r = r0 + wv; r < r1; r += 4)
        acc += h[(size_t)r * 64 + lane];
    sh[t] = acc;
    __syncthreads();
    if (wv == 0) {
        float p = sh[lane] + sh[64 + lane] + sh[128 + lane] + sh[192 + lane];
        p *= 1.0f / fmaxf((float)(r1 - r0), 1.0f);
        float c0 = p * Wc[lane * 3 + 0];
        float c1 = p * Wc[lane * 3 + 1];
        float c2 = p * Wc[lane * 3 + 2];
        for (int o = 32; o > 0; o >>= 1) {
            c0 += __shfl_xor(c0, o);
            c1 += __shfl_xor(c1, o);
            c2 += __shfl_xor(c2, o);
        }
        if (lane == 0) {
            out[g * 3 + 0] = c0 + bc[0];
            out[g * 3 + 1] = c1 + bc[1];
            out[g * 3 + 2] = c2 + bc[2];
        }
    }
}

extern "C" void kernel_launch(void* const* d_in, const int* in_sizes, int n_in,
                              void* d_out, int out_size, void* d_ws, size_t ws_size,
                              hipStream_t stream) {
    const float* x   = (const float*)d_in[0];
    const float* W1  = (const float*)d_in[1];
    const float* b1  = (const float*)d_in[2];
    const float* g1  = (const float*)d_in[3];
    const float* bt1 = (const float*)d_in[4];
    const float* rm1 = (const float*)d_in[5];
    const float* rv1 = (const float*)d_in[6];
    const float* W2  = (const float*)d_in[7];
    const float* b2  = (const float*)d_in[8];
    const float* g2  = (const float*)d_in[9];
    const float* bt2 = (const float*)d_in[10];
    const float* rm2 = (const float*)d_in[11];
    const float* rv2 = (const float*)d_in[12];
    const float* Wc  = (const float*)d_in[13];
    const float* bc  = (const float*)d_in[14];
    const int* ei    = (const int*)d_in[15];
    const int* batch = (const int*)d_in[16];
    const int* srcp = ei;
    const int* dstp = ei + NE;

    char* ws = (char*)d_ws;
    u16*   hpb    = (u16*)(ws);                 // 4 slices x (NN+1)*16 bf16 = 12,800,128 B
    int*   ccount = (int*)(ws + 12800128);      // NCB
    int*   cbase  = (int*)(ws + 12803264);      // NCB+1
    int*   fbase  = (int*)(ws + 12806400);      // NCB
    int*   gcur   = (int*)(ws + 12809536);      // NCB
    int*   offs   = (int*)(ws + 12812672);      // NN
    int*   cntp   = (int*)(ws + 13212672);      // NN
    float* dinv   = (float*)(ws + 13612672);    // NN
    int*   esf    = (int*)(ws + 14012672);      // NE + 387*NCB ints (~14.0 MB)
    float* bufB   = (float*)(ws + 28052672);    // NN*64 fp32 = 25.6 MB
    int*   esc    = (int*)(ws + 28052672);      // NE ints — overlaps bufB (dead before agg1 writes)

    // ---- init: ccount zeroed; per-slice sentinel rows zeroed inside k_cscan ----
    hipMemsetAsync(ccount, 0, NCB * 4, stream);

    // ---- CSR build ----
    k_chist<<<512, 256, 0, stream>>>(dstp, ccount);
    k_cscan<<<1, 256, 0, stream>>>(ccount, cbase, fbase, gcur, (u32*)hpb);
    k_p1<<<(NE + P1_CHUNK - 1) / P1_CHUNK, 1024, 0, stream>>>(srcp, dstp, gcur, esc);
    k_p2<<<NCB, 256, 0, stream>>>(esc, cbase, fbase, esf, offs, cntp, dinv);

    // ---- layer 1 ----
    k_gemm<128><<<(NN + 127) / 128, 256, 0, stream>>>(x, W1, dinv, hpb, NN);
    k_agg<<<AGG_GRID, 256, 0, stream>>>((const u32*)hpb, esf, offs, cntp, dinv, b1, g1, bt1, rm1, rv1, bufB);

    // ---- layer 2 ----
    k_gemm<64><<<(NN + 127) / 128, 256, 0, stream>>>(bufB, W2, dinv, hpb, NN);
    k_agg<<<AGG_GRID, 256, 0, stream>>>((const u32*)hpb, esf, offs, cntp, dinv, b2, g2, bt2, rm2, rv2, bufB);

    // ---- fused mean-pool + classify ----
    k_poolcls<<<NG, 256, 0, stream>>>(bufB, batch, Wc, bc, (float*)d_out);
}

// Round 8
// 394.407 us; speedup vs baseline: 1.2261x; 1.1040x over previous
//
#include <hip/hip_runtime.h>

#define NN 100000
#define NE 3200000
#define NG 512
#define NCB 782           // coarse buckets of 128 nodes: ceil(100000/128)
#define BN_EPS 1e-5f

typedef unsigned short u16;
typedef unsigned int u32;

__device__ __forceinline__ u16 f2bf(float f) {
    u32 u = __float_as_uint(f);
    u += 0x7FFF + ((u >> 16) & 1);  // RNE
    return (u16)(u >> 16);
}

// ================= coarse histogram (LDS-privatized) =================
__global__ __launch_bounds__(256) void k_chist(const int* __restrict__ dst, int* __restrict__ ccount) {
    __shared__ int h[NCB];
    int t = threadIdx.x;
    for (int i = t; i < NCB; i += 256) h[i] = 0;
    __syncthreads();
    int stride = gridDim.x * 256;
    for (int e = blockIdx.x * 256 + t; e < NE; e += stride)
        atomicAdd(&h[dst[e] >> 7], 1);
    __syncthreads();
    for (int i = t; i < NCB; i += 256)
        if (h[i]) atomicAdd(&ccount[i], h[i]);
}

// ========== scan coarse counts -> cbase, padded fine bases, global cursors ==========
__global__ __launch_bounds__(256) void k_cscan(const int* __restrict__ ccount, int* __restrict__ cbase,
                                               int* __restrict__ fbase, int* __restrict__ gcur) {
    __shared__ int sh[256], sh2[256];
    int t = threadIdx.x;
    int v[4], w[4];
    int s = 0, s2 = 0;
#pragma unroll
    for (int j = 0; j < 4; j++) {
        int idx = t * 4 + j;
        int c = (idx < NCB) ? ccount[idx] : 0;
        v[j] = c;
        w[j] = (idx < NCB) ? ((c + 387) & ~3) : 0;  // <=3 pad per node * 128 nodes, x4 aligned
        s += v[j]; s2 += w[j];
    }
    sh[t] = s; sh2[t] = s2;
    __syncthreads();
    for (int off = 1; off < 256; off <<= 1) {
        int x = (t >= off) ? sh[t - off] : 0;
        int x2 = (t >= off) ? sh2[t - off] : 0;
        __syncthreads();
        sh[t] += x; sh2[t] += x2;
        __syncthreads();
    }
    int run = sh[t] - s, run2 = sh2[t] - s2;
#pragma unroll
    for (int j = 0; j < 4; j++) {
        int idx = t * 4 + j;
        if (idx < NCB) { cbase[idx] = run; gcur[idx] = run; fbase[idx] = run2; }
        run += v[j]; run2 += w[j];
    }
    if (t == 255) cbase[NCB] = run;  // == NE
}

// ========== pass 1: coarse binning ==========
// chunk 8192: 391 blocks (full 256-CU coverage vs 196 before); per-(block,bucket)
// runs ~10 edges (~42 B) — half the old 84 B runs, accepted for 2x CU coverage.
#define P1_CHUNK 8192
__global__ __launch_bounds__(1024) void k_p1(const int* __restrict__ src, const int* __restrict__ dst,
                                             int* __restrict__ gcur, int* __restrict__ esc) {
    __shared__ int ccur[NCB];
    const int t = threadIdx.x;
    const int e0 = blockIdx.x * P1_CHUNK;
    for (int i = t; i < NCB; i += 1024) ccur[i] = 0;
    __syncthreads();
    int n = NE - e0; if (n > P1_CHUNK) n = P1_CHUNK;
    // phase 1: block-local histogram
    for (int idx = t; idx < n; idx += 1024)
        atomicAdd(&ccur[dst[e0 + idx] >> 7], 1);
    __syncthreads();
    // phase 2: one global reservation per (block,bucket)
    for (int i = t; i < NCB; i += 1024) {
        int c = ccur[i];
        ccur[i] = (c > 0) ? atomicAdd(&gcur[i], c) : 0;
    }
    __syncthreads();
    // phase 3: scatter (re-read src/dst — L3-hot)
    for (int idx = t; idx < n; idx += 1024) {
        int dd = dst[e0 + idx];
        int s = src[e0 + idx];
        int pos = atomicAdd(&ccur[dd >> 7], 1);
        esc[pos] = s | ((dd & 127) << 17);  // 17b src | 7b dstLocal
    }
}

// ========== pass 2: fine per-node CSR within each coarse bucket; emits offs/cntp/dinv ==========
__global__ __launch_bounds__(256) void k_p2(const int* __restrict__ esc, const int* __restrict__ cbase,
                                            const int* __restrict__ fbase, int* __restrict__ esf,
                                            int* __restrict__ offs, int* __restrict__ cntp,
                                            float* __restrict__ dinv) {
    __shared__ int lcnt[128], loff[128], lcur[128];
    int t = threadIdx.x, b = blockIdx.x;
    int c0 = cbase[b], c1 = cbase[b + 1];
    if (t < 128) lcnt[t] = 0;
    __syncthreads();
    for (int i = c0 + t; i < c1; i += 256) atomicAdd(&lcnt[esc[i] >> 17], 1);
    __syncthreads();
    int p = 0, cnt = 0;
    if (t < 128) { cnt = lcnt[t]; p = (cnt + 3) & ~3; loff[t] = p; }
    __syncthreads();
    for (int off = 1; off < 128; off <<= 1) {
        int x = (t >= off && t < 128) ? loff[t - off] : 0;
        __syncthreads();
        if (t < 128) loff[t] += x;
        __syncthreads();
    }
    int fb = fbase[b];
    int node = (b << 7) + t;
    if (t < 128) {
        int o = fb + loff[t] - p;
        lcur[t] = o;
        if (node < NN) {
            offs[node] = o;
            cntp[node] = p;
            dinv[node] = rsqrtf((float)(cnt + 1));  // +1 self-loop
            for (int q = cnt; q < p; q++) esf[o + q] = NN;  // sentinel -> zero row
        }
    }
    __syncthreads();
    for (int i = c0 + t; i < c1; i += 256) {
        int rec = esc[i];
        int pos = atomicAdd(&lcur[rec >> 17], 1);
        esf[pos] = rec & 0x1FFFF;
    }
}

// ===== GEMM v2: 256-row blocks, W-only LDS staging, direct-global X reads =====
// Old version was LDS-read-bound (12 ds_read_b128 / 128 FMA). Now: stage W once
// (single __syncthreads), X read straight from global — 8 lanes share each row
// address (HW broadcast-coalesce) and 64B lines give 4x L1 reuse across kk.
// 8 rows x 8 cols per thread: 8 LDS reads / 256 FMA (3x better ratio), no xs
// staging writes, no per-chunk barriers.
template <int K>
__global__ __launch_bounds__(256) void k_gemm(const float* __restrict__ X,
                                              const float* __restrict__ W,
                                              const float* __restrict__ dinv,
                                              u16* __restrict__ hp, int M) {
    __shared__ float ws[K * 64];   // 32KB (K=128) / 16KB (K=64)
    const int t = threadIdx.x;
    const int row0 = blockIdx.x * 256;
    const int rg = t >> 3;          // 0..31
    const int f0 = (t & 7) * 8;

    const float4* Wg = (const float4*)W;
    float4* ws4 = (float4*)ws;
#pragma unroll
    for (int i = 0; i < (K * 16) / 256; i++) ws4[t + i * 256] = Wg[t + i * 256];
    __syncthreads();

    float acc[8][8];
#pragma unroll
    for (int j = 0; j < 8; j++)
#pragma unroll
        for (int c = 0; c < 8; c++) acc[j][c] = 0.0f;

    const float* xr[8];
#pragma unroll
    for (int j = 0; j < 8; j++) {
        int row = row0 + rg + 32 * j;
        xr[j] = X + (size_t)(row < M ? row : 0) * K;  // clamp reads, guard stores
    }

    for (int kk = 0; kk < K; kk += 4) {
        float4 xv[8];
#pragma unroll
        for (int j = 0; j < 8; j++) xv[j] = *(const float4*)(xr[j] + kk);
#pragma unroll
        for (int kki = 0; kki < 4; kki++) {
            float4 w0 = *(const float4*)(&ws[(kk + kki) * 64 + f0]);
            float4 w1 = *(const float4*)(&ws[(kk + kki) * 64 + f0 + 4]);
#pragma unroll
            for (int j = 0; j < 8; j++) {
                float a = (&xv[j].x)[kki];
                acc[j][0] = fmaf(a, w0.x, acc[j][0]);
                acc[j][1] = fmaf(a, w0.y, acc[j][1]);
                acc[j][2] = fmaf(a, w0.z, acc[j][2]);
                acc[j][3] = fmaf(a, w0.w, acc[j][3]);
                acc[j][4] = fmaf(a, w1.x, acc[j][4]);
                acc[j][5] = fmaf(a, w1.y, acc[j][5]);
                acc[j][6] = fmaf(a, w1.z, acc[j][6]);
                acc[j][7] = fmaf(a, w1.w, acc[j][7]);
            }
        }
    }

#pragma unroll
    for (int j = 0; j < 8; j++) {
        int row = row0 + rg + 32 * j;
        if (row < M) {
            float di = dinv[row];
            uint4 pk;
            pk.x = (u32)f2bf(acc[j][0] * di) | ((u32)f2bf(acc[j][1] * di) << 16);
            pk.y = (u32)f2bf(acc[j][2] * di) | ((u32)f2bf(acc[j][3] * di) << 16);
            pk.z = (u32)f2bf(acc[j][4] * di) | ((u32)f2bf(acc[j][5] * di) << 16);
            pk.w = (u32)f2bf(acc[j][6] * di) | ((u32)f2bf(acc[j][7] * di) << 16);
            *(uint4*)(hp + (size_t)row * 64 + f0) = pk;
        }
    }
}

// ===== wave-per-node aggregation, half-wave split, 8 gathers in flight =====
// (exact round-0 kernel — proven 61.3 us; slicing/deeper-MLP variants all regressed)
__global__ __launch_bounds__(256) void k_agg(const u32* __restrict__ hp2,
                                             const int* __restrict__ esf,
                                             const int* __restrict__ offs,
                                             const int* __restrict__ cntp,
                                             const float* __restrict__ dinv,
                                             const float* __restrict__ bias,
                                             const float* __restrict__ gam,
                                             const float* __restrict__ bet,
                                             const float* __restrict__ rm,
                                             const float* __restrict__ rv,
                                             float* __restrict__ out) {
    const int lane = threadIdx.x & 63;
    const int half = lane >> 5;
    const int fp = lane & 31;
    const int node = (blockIdx.x * 256 + threadIdx.x) >> 6;
    if (node >= NN) return;
    const int beg = offs[node];
    const int mp = cntp[node];  // multiple of 4 (sentinel-padded)
    float ax = 0.0f, ay = 0.0f;
    for (int c = 0; c < mp; c += 64) {
        int m = mp - c;
        if (m > 64) m = 64;
        int rec = (lane < m) ? esf[beg + c + lane] : NN;
        int j = 0;
        for (; j + 16 <= m; j += 16) {  // 16 edges/iter -> 8 loads in flight
            u32 v[8];
#pragma unroll
            for (int u = 0; u < 8; u++) {
                int s = __shfl(rec, j + 2 * u + half);
                v[u] = hp2[(size_t)s * 32 + fp];
            }
#pragma unroll
            for (int u = 0; u < 8; u++) {
                ax += __uint_as_float(v[u] << 16);
                ay += __uint_as_float(v[u] & 0xFFFF0000u);
            }
        }
        for (; j < m; j += 4) {         // tail (m multiple of 4)
            int s0 = __shfl(rec, j + half);
            int s1 = __shfl(rec, j + 2 + half);
            u32 v0 = hp2[(size_t)s0 * 32 + fp];
            u32 v1 = hp2[(size_t)s1 * 32 + fp];
            ax += __uint_as_float(v0 << 16);
            ay += __uint_as_float(v0 & 0xFFFF0000u);
            ax += __uint_as_float(v1 << 16);
            ay += __uint_as_float(v1 & 0xFFFF0000u);
        }
    }
    ax += __shfl_xor(ax, 32);
    ay += __shfl_xor(ay, 32);
    u32 sv = hp2[(size_t)node * 32 + fp];
    ax += __uint_as_float(sv << 16);
    ay += __uint_as_float(sv & 0xFFFF0000u);

    const float di = dinv[node];
    const int f0 = fp * 2;
    float2 bia = *(const float2*)(bias + f0);
    float2 ga  = *(const float2*)(gam + f0);
    float2 be  = *(const float2*)(bet + f0);
    float2 rme = *(const float2*)(rm + f0);
    float2 rva = *(const float2*)(rv + f0);
    float vx = ax * di + bia.x;
    float vy = ay * di + bia.y;
    float yx = (vx - rme.x) * (ga.x * rsqrtf(rva.x + BN_EPS)) + be.x;
    float yy = (vy - rme.y) * (ga.y * rsqrtf(rva.y + BN_EPS)) + be.y;
    if (half == 0)
        *(float2*)(out + (size_t)node * 64 + f0) = make_float2(fmaxf(yx, 0.0f), fmaxf(yy, 0.0f));
}

// ===== fused mean-pool + classifier: one block per graph, batch sorted, no atomics =====
__global__ __launch_bounds__(256) void k_poolcls(const float* __restrict__ h,
                                                 const int* __restrict__ batch,
                                                 const float* __restrict__ Wc,
                                                 const float* __restrict__ bc,
                                                 float* __restrict__ out) {
    __shared__ float sh[256];
    const int g = blockIdx.x;
    const int t = threadIdx.x;
    const int lane = t & 63;
    const int wv = t >> 6;
    int lo = 0, hi = NN;
    while (lo < hi) { int mid = (lo + hi) >> 1; if (batch[mid] < g) lo = mid + 1; else hi = mid; }
    const int r0 = lo;
    hi = NN;
    while (lo < hi) { int mid = (lo + hi) >> 1; if (batch[mid] < g + 1) lo = mid + 1; else hi = mid; }
    const int r1 = lo;
    float acc = 0.0f;
    for (int r = r0 + wv; r < r1; r += 4)
        acc += h[(size_t)r * 64 + lane];
    sh[t] = acc;
    __syncthreads();
    if (wv == 0) {
        float p = sh[lane] + sh[64 + lane] + sh[128 + lane] + sh[192 + lane];
        p *= 1.0f / fmaxf((float)(r1 - r0), 1.0f);
        float c0 = p * Wc[lane * 3 + 0];
        float c1 = p * Wc[lane * 3 + 1];
        float c2 = p * Wc[lane * 3 + 2];
        for (int o = 32; o > 0; o >>= 1) {
            c0 += __shfl_xor(c0, o);
            c1 += __shfl_xor(c1, o);
            c2 += __shfl_xor(c2, o);
        }
        if (lane == 0) {
            out[g * 3 + 0] = c0 + bc[0];
            out[g * 3 + 1] = c1 + bc[1];
            out[g * 3 + 2] = c2 + bc[2];
        }
    }
}

extern "C" void kernel_launch(void* const* d_in, const int* in_sizes, int n_in,
                              void* d_out, int out_size, void* d_ws, size_t ws_size,
                              hipStream_t stream) {
    const float* x   = (const float*)d_in[0];
    const float* W1  = (const float*)d_in[1];
    const float* b1  = (const float*)d_in[2];
    const float* g1  = (const float*)d_in[3];
    const float* bt1 = (const float*)d_in[4];
    const float* rm1 = (const float*)d_in[5];
    const float* rv1 = (const float*)d_in[6];
    const float* W2  = (const float*)d_in[7];
    const float* b2  = (const float*)d_in[8];
    const float* g2  = (const float*)d_in[9];
    const float* bt2 = (const float*)d_in[10];
    const float* rm2 = (const float*)d_in[11];
    const float* rv2 = (const float*)d_in[12];
    const float* Wc  = (const float*)d_in[13];
    const float* bc  = (const float*)d_in[14];
    const int* ei    = (const int*)d_in[15];
    const int* batch = (const int*)d_in[16];
    const int* srcp = ei;
    const int* dstp = ei + NE;

    char* ws = (char*)d_ws;
    // layout preserved from round 0 (hpb at 0 — keep the alignment that sped up k_agg)
    u16*   hpb    = (u16*)(ws);                 // (NN+1)*64 bf16 = 12,800,128 B
    int*   ccount = (int*)(ws + 12800128);      // NCB
    int*   cbase  = (int*)(ws + 12803264);      // NCB+1
    int*   fbase  = (int*)(ws + 12806400);      // NCB
    int*   gcur   = (int*)(ws + 12809536);      // NCB
    int*   offs   = (int*)(ws + 12812672);      // NN
    int*   cntp   = (int*)(ws + 13212672);      // NN
    float* dinv   = (float*)(ws + 13612672);    // NN
    int*   esf    = (int*)(ws + 14012672);      // NE + 387*NCB ints (~14.0 MB)
    float* bufB   = (float*)(ws + 28052672);    // NN*64 fp32 = 25.6 MB
    int*   esc    = (int*)(ws + 28052672);      // NE ints — overlaps bufB (dead before agg1 writes)

    // ---- single init memset: sentinel zero row (128 B) + ccount (3128 B), adjacent ----
    hipMemsetAsync(hpb + (size_t)NN * 64, 0, 128 + NCB * 4, stream);

    // ---- CSR build ----
    k_chist<<<512, 256, 0, stream>>>(dstp, ccount);
    k_cscan<<<1, 256, 0, stream>>>(ccount, cbase, fbase, gcur);
    k_p1<<<(NE + P1_CHUNK - 1) / P1_CHUNK, 1024, 0, stream>>>(srcp, dstp, gcur, esc);
    k_p2<<<NCB, 256, 0, stream>>>(esc, cbase, fbase, esf, offs, cntp, dinv);

    // ---- layer 1 ----
    k_gemm<128><<<(NN + 255) / 256, 256, 0, stream>>>(x, W1, dinv, hpb, NN);
    k_agg<<<(NN * 64 + 255) / 256, 256, 0, stream>>>((const u32*)hpb, esf, offs, cntp, dinv, b1, g1, bt1, rm1, rv1, bufB);

    // ---- layer 2 ----
    k_gemm<64><<<(NN + 255) / 256, 256, 0, stream>>>(bufB, W2, dinv, hpb, NN);
    k_agg<<<(NN * 64 + 255) / 256, 256, 0, stream>>>((const u32*)hpb, esf, offs, cntp, dinv, b2, g2, bt2, rm2, rv2, bufB);

    // ---- fused mean-pool + classify ----
    k_poolcls<<<NG, 256, 0, stream>>>(bufB, batch, Wc, bc, (float*)d_out);
}